// Round 5
// baseline (25882.483 us; speedup 1.0000x reference)
//
#include <hip/hip_runtime.h>
#include <math.h>

#define Hd 1024
#define Ed 512
#define Bv 64
#define Sv 128
#define Tv 64
#define Vv 32000
#define NB 256

typedef __attribute__((ext_vector_type(8))) short bf16x8;
typedef __attribute__((ext_vector_type(4))) float f32x4;

__device__ __forceinline__ float sigf(float x){ return 1.0f/(1.0f + expf(-x)); }
__device__ __forceinline__ unsigned short f2bf(float f){
  unsigned u = __float_as_uint(f);
  return (unsigned short)((u + 0x7FFFu + ((u>>16)&1u)) >> 16);
}
__device__ __forceinline__ float bf2f(unsigned short b){ return __uint_as_float(((unsigned)b)<<16); }
__device__ __forceinline__ void split3(float v, unsigned short& s0, unsigned short& s1, unsigned short& s2){
  s0 = f2bf(v);
  float r1 = v - bf2f(s0);
  s1 = f2bf(r1);
  s2 = f2bf(r1 - bf2f(s1));
}
#define MF(A,B,C) __builtin_amdgcn_mfma_f32_16x16x32_bf16(A,B,C,0,0,0)

// ---- ws layout (float offsets) ----
// [0,131072)            cbuf[2]
// [131072,327680)       H0[2],H1[2],H2[2] bf16 (as shorts)
// [327680,6619136)      Xe 3-way [128][64][512]
// [6619136,16056320)    We 3-way [4096][1536]
// [16056320,25493504)   Wd 3-way [4096][1536]
// [25493504,25501696)   toku: 63*64 u64 argmax slots (memset 0)
// [25501696,25502208)   barrier counters 512 int (memset 0)
#define OFF_HB   131072
#define OFF_XE   327680
#define OFF_WE   6619136
#define OFF_WD   16056320
#define OFF_TOK  25493504
#define OFF_CNT  25501696
#define NEED_FL  25502208

// ---------------- prep kernels ----------------

__global__ __launch_bounds__(256) void k_wsplit3(
    const float* __restrict__ Wih, const float* __restrict__ Whh,
    unsigned short* __restrict__ d0, unsigned short* __restrict__ d1, unsigned short* __restrict__ d2)
{
  const int row = blockIdx.x;
  const int tid = threadIdx.x;
  #pragma unroll
  for (int i = 0; i < 6; ++i){
    int e = tid + 256*i;
    float v = (e < 512) ? Wih[(long)row*512 + e] : Whh[(long)row*1024 + (e-512)];
    unsigned short s0,s1,s2; split3(v, s0,s1,s2);
    d0[(long)row*1536 + e] = s0;
    d1[(long)row*1536 + e] = s1;
    d2[(long)row*1536 + e] = s2;
  }
}

__global__ __launch_bounds__(256) void k_prep_xe(
    const int* __restrict__ src, const float* __restrict__ enc_emb,
    unsigned short* __restrict__ X0, unsigned short* __restrict__ X1, unsigned short* __restrict__ X2)
{
  const int b = blockIdx.x, tid = threadIdx.x;
  const int t = b >> 6, m = b & 63;
  const float* srow = enc_emb + (long)src[m*Sv + t]*Ed;
  const long off = ((long)t*64 + m)*Ed;
  #pragma unroll
  for (int i = 0; i < 2; ++i){
    int e = tid + 256*i;
    unsigned short s0,s1,s2; split3(srow[e], s0,s1,s2);
    X0[off+e] = s0; X1[off+e] = s1; X2[off+e] = s2;
  }
}

// ---------------- grid barrier ----------------
__device__ __forceinline__ void gbar(int* cnt, int idx){
  __syncthreads();
  if (threadIdx.x == 0){
    __threadfence();
    __hip_atomic_fetch_add(&cnt[idx], 1, __ATOMIC_RELEASE, __HIP_MEMORY_SCOPE_AGENT);
    while (__hip_atomic_load(&cnt[idx], __ATOMIC_ACQUIRE, __HIP_MEMORY_SCOPE_AGENT) < NB)
      __builtin_amdgcn_s_sleep(8);
    __threadfence();
  }
  __syncthreads();
}

// ---------------- LSTM phase (round-4 k_step2 body, 6-term fp32-equivalent) ----------------
template<bool DEC>
__device__ __forceinline__ void lstm_phase(
    int b, int tid, int tj,
    const unsigned short* __restrict__ W0s, const unsigned short* __restrict__ W1s,
    const unsigned short* __restrict__ W2s, const float* __restrict__ bias,
    const unsigned short* __restrict__ X0, const unsigned short* __restrict__ X1,
    const unsigned short* __restrict__ X2,
    const int* __restrict__ trg, const int* __restrict__ tf,
    const float* __restrict__ dec_emb, const unsigned long long* __restrict__ toku,
    const unsigned short* __restrict__ H0in, const unsigned short* __restrict__ H1in,
    const unsigned short* __restrict__ H2in,
    const float* __restrict__ c_in, float* __restrict__ c_out,
    unsigned short* __restrict__ H0o, unsigned short* __restrict__ H1o,
    unsigned short* __restrict__ H2o,
    float (*g4)[32][16], int* stok)
{
  const int g = tid >> 6, lane = tid & 63;
  const int l15 = lane & 15, lk = lane >> 4;
  const int jh0 = (b & 63) * 16;
  const int m0 = (b >> 6) * 32;
  const int n = g*Hd + jh0 + l15;
  const unsigned short* w0 = W0s + (long)n*1536;
  const unsigned short* w1 = W1s + (long)n*1536;
  const unsigned short* w2 = W2s + (long)n*1536;

  if (DEC){
    if (tid < 32){
      int m = m0 + tid, tk;
      if (tj == 0) tk = trg[m*Tv];
      else if (tf[tj] > 0) tk = trg[m*Tv + tj];
      else tk = (int)(~(unsigned)toku[(long)(tj-1)*64 + m]);
      stok[tid] = tk;
    }
    __syncthreads();
  }

  f32x4 acc0 = (f32x4){0.f,0.f,0.f,0.f};
  f32x4 acc1 = (f32x4){0.f,0.f,0.f,0.f};

  // x part: K = 0..511
  if (DEC){
    const float* e0 = dec_emb + (long)stok[l15]*Ed;
    const float* e1 = dec_emb + (long)stok[16 + l15]*Ed;
    #pragma unroll 2
    for (int kt = 0; kt < 16; ++kt){
      const int k0 = kt*32 + lk*8;
      bf16x8 b0 = *(const bf16x8*)(w0 + k0);
      bf16x8 b1v = *(const bf16x8*)(w1 + k0);
      bf16x8 b2 = *(const bf16x8*)(w2 + k0);
      bf16x8 a00,a01,a02,a10,a11,a12;
      {
        float4 pa = *(const float4*)(e0 + k0);
        float4 pb = *(const float4*)(e0 + k0 + 4);
        float fv[8] = {pa.x,pa.y,pa.z,pa.w,pb.x,pb.y,pb.z,pb.w};
        #pragma unroll
        for (int e=0;e<8;++e){ unsigned short s0,s1,s2; split3(fv[e],s0,s1,s2);
          a00[e]=(short)s0; a01[e]=(short)s1; a02[e]=(short)s2; }
      }
      {
        float4 pa = *(const float4*)(e1 + k0);
        float4 pb = *(const float4*)(e1 + k0 + 4);
        float fv[8] = {pa.x,pa.y,pa.z,pa.w,pb.x,pb.y,pb.z,pb.w};
        #pragma unroll
        for (int e=0;e<8;++e){ unsigned short s0,s1,s2; split3(fv[e],s0,s1,s2);
          a10[e]=(short)s0; a11[e]=(short)s1; a12[e]=(short)s2; }
      }
      acc0 = MF(a00,b0,acc0); acc0 = MF(a01,b0,acc0); acc0 = MF(a00,b1v,acc0);
      acc0 = MF(a02,b0,acc0); acc0 = MF(a00,b2,acc0); acc0 = MF(a01,b1v,acc0);
      acc1 = MF(a10,b0,acc1); acc1 = MF(a11,b0,acc1); acc1 = MF(a10,b1v,acc1);
      acc1 = MF(a12,b0,acc1); acc1 = MF(a10,b2,acc1); acc1 = MF(a11,b1v,acc1);
    }
  } else {
    const long ra0x = (long)(m0 + l15)*Ed;
    const long ra1x = (long)(m0 + 16 + l15)*Ed;
    #pragma unroll 2
    for (int kt = 0; kt < 16; ++kt){
      const int k0 = kt*32 + lk*8;
      bf16x8 b0 = *(const bf16x8*)(w0 + k0);
      bf16x8 b1v = *(const bf16x8*)(w1 + k0);
      bf16x8 b2 = *(const bf16x8*)(w2 + k0);
      bf16x8 a00 = *(const bf16x8*)(X0 + ra0x + k0);
      bf16x8 a01 = *(const bf16x8*)(X1 + ra0x + k0);
      bf16x8 a02 = *(const bf16x8*)(X2 + ra0x + k0);
      bf16x8 a10 = *(const bf16x8*)(X0 + ra1x + k0);
      bf16x8 a11 = *(const bf16x8*)(X1 + ra1x + k0);
      bf16x8 a12 = *(const bf16x8*)(X2 + ra1x + k0);
      acc0 = MF(a00,b0,acc0); acc0 = MF(a01,b0,acc0); acc0 = MF(a00,b1v,acc0);
      acc0 = MF(a02,b0,acc0); acc0 = MF(a00,b2,acc0); acc0 = MF(a01,b1v,acc0);
      acc1 = MF(a10,b0,acc1); acc1 = MF(a11,b0,acc1); acc1 = MF(a10,b1v,acc1);
      acc1 = MF(a12,b0,acc1); acc1 = MF(a10,b2,acc1); acc1 = MF(a11,b1v,acc1);
    }
  }
  // h part: K = 512..1535
  {
    const long ra0h = (long)(m0 + l15)*Hd;
    const long ra1h = (long)(m0 + 16 + l15)*Hd;
    #pragma unroll 2
    for (int kt = 0; kt < 32; ++kt){
      const int kw = 512 + kt*32 + lk*8;
      const int ko = kt*32 + lk*8;
      bf16x8 b0 = *(const bf16x8*)(w0 + kw);
      bf16x8 b1v = *(const bf16x8*)(w1 + kw);
      bf16x8 b2 = *(const bf16x8*)(w2 + kw);
      bf16x8 a00 = *(const bf16x8*)(H0in + ra0h + ko);
      bf16x8 a01 = *(const bf16x8*)(H1in + ra0h + ko);
      bf16x8 a02 = *(const bf16x8*)(H2in + ra0h + ko);
      bf16x8 a10 = *(const bf16x8*)(H0in + ra1h + ko);
      bf16x8 a11 = *(const bf16x8*)(H1in + ra1h + ko);
      bf16x8 a12 = *(const bf16x8*)(H2in + ra1h + ko);
      acc0 = MF(a00,b0,acc0); acc0 = MF(a01,b0,acc0); acc0 = MF(a00,b1v,acc0);
      acc0 = MF(a02,b0,acc0); acc0 = MF(a00,b2,acc0); acc0 = MF(a01,b1v,acc0);
      acc1 = MF(a10,b0,acc1); acc1 = MF(a11,b0,acc1); acc1 = MF(a10,b1v,acc1);
      acc1 = MF(a12,b0,acc1); acc1 = MF(a10,b2,acc1); acc1 = MF(a11,b1v,acc1);
    }
  }

  #pragma unroll
  for (int r = 0; r < 4; ++r){
    g4[g][lk*4 + r][l15]      = acc0[r];
    g4[g][16 + lk*4 + r][l15] = acc1[r];
  }
  __syncthreads();

  #pragma unroll
  for (int rep = 0; rep < 2; ++rep){
    const int mloc = (tid >> 4) + rep*16;
    const int cl = tid & 15;
    const int col = jh0 + cl;
    float ig = g4[0][mloc][cl] + bias[0*Hd + col];
    float fg = g4[1][mloc][cl] + bias[1*Hd + col];
    float gg = g4[2][mloc][cl] + bias[2*Hd + col];
    float og = g4[3][mloc][cl] + bias[3*Hd + col];
    long idx = (long)(m0 + mloc)*Hd + col;
    float c = c_in[idx];
    float cn = sigf(fg)*c + sigf(ig)*tanhf(gg);
    float hn = sigf(og)*tanhf(cn);
    c_out[idx] = cn;
    unsigned short s0,s1,s2; split3(hn, s0,s1,s2);
    H0o[idx] = s0; H1o[idx] = s1; H2o[idx] = s2;
  }
}

// ---------------- FC + fused argmax phase ----------------
__device__ __forceinline__ void fc_phase(
    int b, int tid, int j,
    const unsigned short* __restrict__ hhi, const unsigned short* __restrict__ hlo,
    const float* __restrict__ Wfc, const float* __restrict__ bfc,
    float* __restrict__ out, unsigned long long* __restrict__ tslot,
    unsigned long long* amax)
{
  if (tid < 64) amax[tid] = 0ULL;
  __syncthreads();
  const int wv = tid >> 6, lane = tid & 63;
  const int l15 = lane & 15, lk = lane >> 4;
  const int vbase = b*128 + wv*32;
  const int v0 = vbase + l15, v1 = vbase + 16 + l15;
  const float* w0r = Wfc + (long)v0*Hd;
  const float* w1r = Wfc + (long)v1*Hd;

  f32x4 acc[2][4];
  #pragma unroll
  for (int nv=0; nv<2; ++nv)
    #pragma unroll
    for (int mt=0; mt<4; ++mt) acc[nv][mt] = (f32x4){0.f,0.f,0.f,0.f};

  #pragma unroll 2
  for (int kt = 0; kt < 32; ++kt){
    const int k0 = kt*32 + lk*8;
    bf16x8 bh0, bl0, bh1, bl1;
    {
      float4 pa = *(const float4*)(w0r + k0);
      float4 pb = *(const float4*)(w0r + k0 + 4);
      float fv[8] = {pa.x,pa.y,pa.z,pa.w,pb.x,pb.y,pb.z,pb.w};
      #pragma unroll
      for (int e=0;e<8;++e){ unsigned short h = f2bf(fv[e]);
        bh0[e]=(short)h; bl0[e]=(short)f2bf(fv[e]-bf2f(h)); }
    }
    {
      float4 pa = *(const float4*)(w1r + k0);
      float4 pb = *(const float4*)(w1r + k0 + 4);
      float fv[8] = {pa.x,pa.y,pa.z,pa.w,pb.x,pb.y,pb.z,pb.w};
      #pragma unroll
      for (int e=0;e<8;++e){ unsigned short h = f2bf(fv[e]);
        bh1[e]=(short)h; bl1[e]=(short)f2bf(fv[e]-bf2f(h)); }
    }
    #pragma unroll
    for (int mt=0; mt<4; ++mt){
      const int row = mt*16 + l15;
      bf16x8 ah = *(const bf16x8*)(hhi + (long)row*Hd + k0);
      bf16x8 al = *(const bf16x8*)(hlo + (long)row*Hd + k0);
      acc[0][mt] = MF(ah, bh0, acc[0][mt]);
      acc[0][mt] = MF(al, bh0, acc[0][mt]);
      acc[0][mt] = MF(ah, bl0, acc[0][mt]);
      acc[1][mt] = MF(ah, bh1, acc[1][mt]);
      acc[1][mt] = MF(al, bh1, acc[1][mt]);
      acc[1][mt] = MF(ah, bl1, acc[1][mt]);
    }
  }
  float bb0 = bfc[v0], bb1 = bfc[v1];
  #pragma unroll
  for (int mt=0; mt<4; ++mt){
    #pragma unroll
    for (int r=0; r<4; ++r){
      int m = mt*16 + lk*4 + r;
      float f0 = acc[0][mt][r] + bb0;
      float f1 = acc[1][mt][r] + bb1;
      out[((long)m*Tv + (j+1))*(long)Vv + v0] = f0;
      out[((long)m*Tv + (j+1))*(long)Vv + v1] = f1;
      unsigned u0 = __float_as_uint(f0); u0 ^= (u0 >> 31) ? 0xFFFFFFFFu : 0x80000000u;
      unsigned u1 = __float_as_uint(f1); u1 ^= (u1 >> 31) ? 0xFFFFFFFFu : 0x80000000u;
      unsigned long long c0 = ((unsigned long long)u0 << 32) | (unsigned)(~v0);
      unsigned long long c1 = ((unsigned long long)u1 << 32) | (unsigned)(~v1);
      unsigned long long c = c0 > c1 ? c0 : c1;
      #pragma unroll
      for (int d=1; d<16; d<<=1){
        unsigned long long o = __shfl_xor(c, d);
        if (o > c) c = o;
      }
      if (l15 == 0) atomicMax(&amax[m], c);
    }
  }
  __syncthreads();
  if (tid < 64) atomicMax(tslot + tid, amax[tid]);
}

// ---------------- the mega kernel ----------------
__global__ __launch_bounds__(256, 1) void k_mega(
    const int* __restrict__ trg, const int* __restrict__ tf,
    const float* __restrict__ dec_emb,
    const float* __restrict__ b_e, const float* __restrict__ b_d,
    const float* __restrict__ Wfc, const float* __restrict__ bfc,
    float* __restrict__ out, float* __restrict__ ws)
{
  __shared__ float g4[4][32][16];
  __shared__ int stok[32];
  __shared__ unsigned long long amax[64];

  const int b = blockIdx.x, tid = threadIdx.x;
  float* cb[2] = { ws, ws + 65536 };
  unsigned short* HB = (unsigned short*)(ws + OFF_HB);
  unsigned short* H0[2] = { HB,          HB + 65536 };
  unsigned short* H1[2] = { HB + 131072, HB + 196608 };
  unsigned short* H2[2] = { HB + 262144, HB + 327680 };
  const unsigned short* Xe0 = (const unsigned short*)(ws + OFF_XE);
  const unsigned short* Xe1 = Xe0 + 4194304;
  const unsigned short* Xe2 = Xe0 + 8388608;
  const unsigned short* We0 = (const unsigned short*)(ws + OFF_WE);
  const unsigned short* We1 = We0 + 6291456;
  const unsigned short* We2 = We0 + 12582912;
  const unsigned short* Wd0 = (const unsigned short*)(ws + OFF_WD);
  const unsigned short* Wd1 = Wd0 + 6291456;
  const unsigned short* Wd2 = Wd0 + 12582912;
  unsigned long long* toku = (unsigned long long*)(ws + OFF_TOK);
  int* cnt = (int*)(ws + OFF_CNT);
  int bar = 0;

  // phase -1: zero c / H3 state and out[:,0,:]
  for (long i = (long)b*256 + tid; i < 327680; i += (long)NB*256) ws[i] = 0.f;
  for (long r = (long)b*256 + tid; r < (long)Bv*Vv; r += (long)NB*256){
    long m = r / Vv, v = r - m*Vv;
    out[m*(long)Tv*Vv + v] = 0.f;
  }
  gbar(cnt, bar++);

  int cur = 0;
  for (int t = 0; t < Sv; ++t){
    if (b < 128)
      lstm_phase<false>(b, tid, t, We0, We1, We2, b_e,
          Xe0 + (long)t*32768, Xe1 + (long)t*32768, Xe2 + (long)t*32768,
          (const int*)0, (const int*)0, (const float*)0, (const unsigned long long*)0,
          H0[cur], H1[cur], H2[cur], cb[cur], cb[cur^1],
          H0[cur^1], H1[cur^1], H2[cur^1], g4, stok);
    gbar(cnt, bar++);
    cur ^= 1;
  }
  for (int j = 0; j < Tv-1; ++j){
    if (b < 128)
      lstm_phase<true>(b, tid, j, Wd0, Wd1, Wd2, b_d,
          (const unsigned short*)0, (const unsigned short*)0, (const unsigned short*)0,
          trg, tf, dec_emb, toku,
          H0[cur], H1[cur], H2[cur], cb[cur], cb[cur^1],
          H0[cur^1], H1[cur^1], H2[cur^1], g4, stok);
    gbar(cnt, bar++);
    cur ^= 1;
    if (b < 250)
      fc_phase(b, tid, j, H0[cur], H1[cur], Wfc, bfc, out, toku + (long)j*64, amax);
    gbar(cnt, bar++);
  }
}

// ---------------- fallback (round-2 proven path, used only if ws too small) ----------------

__global__ __launch_bounds__(256) void k_initC(float* __restrict__ ws, float* __restrict__ out){
  long i = (long)blockIdx.x*256 + threadIdx.x;
  if (i < 262144){ ws[i] = 0.f; }
  else {
    long r = i - 262144;
    long m = r / Vv, v = r % Vv;
    out[m*Tv*(long)Vv + v] = 0.f;
  }
}

__global__ __launch_bounds__(256) void k_stepC(
    int mode, int t,
    const int* __restrict__ tok_src, const int* __restrict__ tf_mask,
    const int* __restrict__ token_buf, const float* __restrict__ emb,
    const float* __restrict__ Wih, const float* __restrict__ Whh,
    const float* __restrict__ bias,
    const float* __restrict__ h_in, const float* __restrict__ c_in,
    float* __restrict__ h_out, float* __restrict__ c_out,
    unsigned short* __restrict__ hsp_hi, unsigned short* __restrict__ hsp_lo)
{
  __shared__ __align__(16) float tile[8*1536];
  __shared__ float gbuf[4*8*32];
  __shared__ int toks[8];
  const int tid = threadIdx.x;
  const int m0 = blockIdx.y*8, jh0 = blockIdx.x*32;
  if (tid < 8){
    int m = m0 + tid; int tok;
    if (mode == 0) tok = tok_src[m*Sv + t];
    else { if (t == 0) tok = tok_src[m*Tv];
           else tok = (tf_mask[t] > 0) ? tok_src[m*Tv + t] : token_buf[m]; }
    toks[tid] = tok;
  }
  __syncthreads();
  { float4* t4 = (float4*)tile;
    #pragma unroll
    for (int r = 0; r < 12; ++r){
      int f = tid + 256*r; int row = f / 384, o = f % 384; float4 v;
      if (o < 128) v = ((const float4*)(emb + (long)toks[row]*Ed))[o];
      else         v = ((const float4*)(h_in + (long)(m0+row)*Hd))[o-128];
      t4[row*384 + o] = v; } }
  __syncthreads();
  const int g = tid >> 6, s = tid & 63, jl = s & 31, mg = s >> 5;
  const int col = g*Hd + jh0 + jl;
  const float4* wx = (const float4*)(Wih + (long)col*Ed);
  const float4* wh = (const float4*)(Whh + (long)col*Hd);
  const float4* t4 = (const float4*)tile;
  const int mb = mg*4;
  float bq = bias[col];
  float a0=bq, a1=bq, a2=bq, a3=bq;
  for (int k = 0; k < 128; ++k){
    float4 w = wx[k];
    float4 v0 = t4[(mb+0)*384 + k]; float4 v1 = t4[(mb+1)*384 + k];
    float4 v2 = t4[(mb+2)*384 + k]; float4 v3 = t4[(mb+3)*384 + k];
    a0 += w.x*v0.x + w.y*v0.y + w.z*v0.z + w.w*v0.w;
    a1 += w.x*v1.x + w.y*v1.y + w.z*v1.z + w.w*v1.w;
    a2 += w.x*v2.x + w.y*v2.y + w.z*v2.z + w.w*v2.w;
    a3 += w.x*v3.x + w.y*v3.y + w.z*v3.z + w.w*v3.w;
  }
  for (int k = 0; k < 256; ++k){
    float4 w = wh[k];
    float4 v0 = t4[(mb+0)*384 + 128 + k]; float4 v1 = t4[(mb+1)*384 + 128 + k];
    float4 v2 = t4[(mb+2)*384 + 128 + k]; float4 v3 = t4[(mb+3)*384 + 128 + k];
    a0 += w.x*v0.x + w.y*v0.y + w.z*v0.z + w.w*v0.w;
    a1 += w.x*v1.x + w.y*v1.y + w.z*v1.z + w.w*v1.w;
    a2 += w.x*v2.x + w.y*v2.y + w.z*v2.z + w.w*v2.w;
    a3 += w.x*v3.x + w.y*v3.y + w.z*v3.z + w.w*v3.w;
  }
  gbuf[g*256 + (mb+0)*32 + jl] = a0; gbuf[g*256 + (mb+1)*32 + jl] = a1;
  gbuf[g*256 + (mb+2)*32 + jl] = a2; gbuf[g*256 + (mb+3)*32 + jl] = a3;
  __syncthreads();
  const int ml = tid >> 5, j2 = tid & 31;
  float ig = gbuf[0*256 + ml*32 + j2];
  float fg = gbuf[1*256 + ml*32 + j2];
  float gg = gbuf[2*256 + ml*32 + j2];
  float og = gbuf[3*256 + ml*32 + j2];
  long idx = (long)(m0+ml)*Hd + jh0 + j2;
  float c = c_in[idx];
  float cn = sigf(fg)*c + sigf(ig)*tanhf(gg);
  float hn = sigf(og)*tanhf(cn);
  c_out[idx] = cn; h_out[idx] = hn;
  unsigned short hh = f2bf(hn);
  hsp_hi[idx] = hh; hsp_lo[idx] = f2bf(hn - bf2f(hh));
}

__global__ __launch_bounds__(256) void k_fcC(
    int j, const unsigned short* __restrict__ hhi, const unsigned short* __restrict__ hlo,
    const float* __restrict__ Wfc, const float* __restrict__ bfc, float* __restrict__ out)
{
  const int tid = threadIdx.x;
  const int wv = tid >> 6, lane = tid & 63;
  const int l15 = lane & 15, lk = lane >> 4;
  const int vcol = blockIdx.x*64 + wv*16 + l15;
  const float* wrow = Wfc + (long)vcol*Hd;
  f32x4 acc[4];
  #pragma unroll
  for (int mt=0; mt<4; ++mt) acc[mt] = (f32x4){0.f,0.f,0.f,0.f};
  #pragma unroll 2
  for (int kt = 0; kt < 32; ++kt){
    const int k0 = kt*32 + lk*8;
    float4 wa = *(const float4*)(wrow + k0);
    float4 wb = *(const float4*)(wrow + k0 + 4);
    float wf[8] = {wa.x,wa.y,wa.z,wa.w,wb.x,wb.y,wb.z,wb.w};
    bf16x8 bh, bl;
    #pragma unroll
    for (int e=0;e<8;++e){
      unsigned short h = f2bf(wf[e]);
      bh[e] = (short)h; bl[e] = (short)f2bf(wf[e] - bf2f(h));
    }
    #pragma unroll
    for (int mt=0; mt<4; ++mt){
      const int row = mt*16 + l15;
      bf16x8 ah = *(const bf16x8*)(hhi + row*Hd + k0);
      bf16x8 al = *(const bf16x8*)(hlo + row*Hd + k0);
      acc[mt] = MF(ah, bh, acc[mt]);
      acc[mt] = MF(al, bh, acc[mt]);
      acc[mt] = MF(ah, bl, acc[mt]);
    }
  }
  float bb = bfc[vcol];
  #pragma unroll
  for (int mt=0; mt<4; ++mt)
    #pragma unroll
    for (int r=0; r<4; ++r){
      int m = mt*16 + lk*4 + r;
      out[((long)m*Tv + (j+1))*(long)Vv + vcol] = acc[mt][r] + bb;
    }
}

__global__ __launch_bounds__(256) void k_argmaxC(
    int j, const float* __restrict__ out, int* __restrict__ token_buf)
{
  __shared__ float sval[256];
  __shared__ int   sidx[256];
  const int m = blockIdx.x, tid = threadIdx.x;
  const float* base = out + ((long)m*Tv + (j+1))*(long)Vv;
  float best = -INFINITY; int bi = 0;
  for (int v = tid; v < Vv; v += 256){
    float f = base[v];
    if (f > best){ best = f; bi = v; }
  }
  sval[tid] = best; sidx[tid] = bi;
  __syncthreads();
  for (int s2 = 128; s2 > 0; s2 >>= 1){
    if (tid < s2){
      float ov = sval[tid+s2]; int oi = sidx[tid+s2];
      if (ov > sval[tid] || (ov == sval[tid] && oi < sidx[tid])){
        sval[tid] = ov; sidx[tid] = oi;
      }
    }
    __syncthreads();
  }
  if (tid == 0) token_buf[m] = sidx[0];
}

extern "C" void kernel_launch(void* const* d_in, const int* in_sizes, int n_in,
                              void* d_out, int out_size, void* d_ws, size_t ws_size,
                              hipStream_t stream)
{
  const int*   src     = (const int*)  d_in[0];
  const int*   trg     = (const int*)  d_in[1];
  const int*   tf      = (const int*)  d_in[2];
  const float* enc_emb = (const float*)d_in[3];
  const float* dec_emb = (const float*)d_in[4];
  const float* Wih_e   = (const float*)d_in[5];
  const float* Whh_e   = (const float*)d_in[6];
  const float* b_e     = (const float*)d_in[7];
  const float* Wih_d   = (const float*)d_in[8];
  const float* Whh_d   = (const float*)d_in[9];
  const float* b_d     = (const float*)d_in[10];
  const float* Wfc     = (const float*)d_in[11];
  const float* bfc     = (const float*)d_in[12];
  float* out = (float*)d_out;
  float* ws  = (float*)d_ws;

  if (ws_size >= (size_t)NEED_FL * 4ULL){
    unsigned short* We0 = (unsigned short*)(ws + OFF_WE);
    unsigned short* We1 = We0 + 6291456;
    unsigned short* We2 = We0 + 12582912;
    unsigned short* Wd0 = (unsigned short*)(ws + OFF_WD);
    unsigned short* Wd1 = Wd0 + 6291456;
    unsigned short* Wd2 = Wd0 + 12582912;
    unsigned short* Xe0 = (unsigned short*)(ws + OFF_XE);
    unsigned short* Xe1 = Xe0 + 4194304;
    unsigned short* Xe2 = Xe0 + 8388608;

    // zero argmax slots + barrier counters (one contiguous region)
    hipMemsetAsync((void*)(ws + OFF_TOK), 0, (size_t)(NEED_FL - OFF_TOK) * 4ULL, stream);
    k_wsplit3<<<4096, 256, 0, stream>>>(Wih_e, Whh_e, We0, We1, We2);
    k_wsplit3<<<4096, 256, 0, stream>>>(Wih_d, Whh_d, Wd0, Wd1, Wd2);
    k_prep_xe<<<8192, 256, 0, stream>>>(src, enc_emb, Xe0, Xe1, Xe2);
    k_mega<<<NB, 256, 0, stream>>>(trg, tf, dec_emb, b_e, b_d, Wfc, bfc, out, ws);
  } else {
    // fallback: round-2 proven multi-kernel path
    float* hbuf[2] = { ws,            ws + 65536 };
    float* cbuf[2] = { ws + 131072,   ws + 196608 };
    int*   tokbuf  = (int*)(ws + 262144);
    unsigned short* hsp_hi = (unsigned short*)(ws + 262208);
    unsigned short* hsp_lo = (unsigned short*)(ws + 262208 + 32768);

    k_initC<<<9024, 256, 0, stream>>>(ws, out);
    int cur = 0;
    for (int t = 0; t < Sv; ++t){
      k_stepC<<<dim3(32,8), 256, 0, stream>>>(0, t, src, tf, tokbuf, enc_emb,
          Wih_e, Whh_e, b_e, hbuf[cur], cbuf[cur], hbuf[cur^1], cbuf[cur^1], hsp_hi, hsp_lo);
      cur ^= 1;
    }
    for (int j = 0; j < Tv-1; ++j){
      k_stepC<<<dim3(32,8), 256, 0, stream>>>(1, j, trg, tf, tokbuf, dec_emb,
          Wih_d, Whh_d, b_d, hbuf[cur], cbuf[cur], hbuf[cur^1], cbuf[cur^1], hsp_hi, hsp_lo);
      cur ^= 1;
      k_fcC<<<500, 256, 0, stream>>>(j, hsp_hi, hsp_lo, Wfc, bfc, out);
      if (j < Tv-2) k_argmaxC<<<64, 256, 0, stream>>>(j, out, tokbuf);
    }
  }
}

// Round 6
// 17462.978 us; speedup vs baseline: 1.4821x; 1.4821x over previous
//
#include <hip/hip_runtime.h>
#include <math.h>

#define Hd 1024
#define Ed 512
#define Bv 64
#define Sv 128
#define Tv 64
#define Vv 32000
#define NB 256

typedef __attribute__((ext_vector_type(8))) short bf16x8;
typedef __attribute__((ext_vector_type(4))) float f32x4;

__device__ __forceinline__ float sigf(float x){ return 1.0f/(1.0f + expf(-x)); }
__device__ __forceinline__ unsigned short f2bf(float f){
  unsigned u = __float_as_uint(f);
  return (unsigned short)((u + 0x7FFFu + ((u>>16)&1u)) >> 16);
}
__device__ __forceinline__ float bf2f(unsigned short b){ return __uint_as_float(((unsigned)b)<<16); }
__device__ __forceinline__ void split3(float v, unsigned short& s0, unsigned short& s1, unsigned short& s2){
  s0 = f2bf(v);
  float r1 = v - bf2f(s0);
  s1 = f2bf(r1);
  s2 = f2bf(r1 - bf2f(s1));
}
#define MF(A,B,C) __builtin_amdgcn_mfma_f32_16x16x32_bf16(A,B,C,0,0,0)

// ---- ws layout (float offsets) ----
#define OFF_HB   131072
#define OFF_XE   327680
#define OFF_WE   6619136
#define OFF_WD   16056320
#define OFF_TOK  25493504
#define OFF_CNT  25501696
#define NEED_FL  25502208

// ---------------- prep kernels ----------------

__global__ __launch_bounds__(256) void k_wsplit3(
    const float* __restrict__ Wih, const float* __restrict__ Whh,
    unsigned short* __restrict__ d0, unsigned short* __restrict__ d1, unsigned short* __restrict__ d2)
{
  const int row = blockIdx.x;
  const int tid = threadIdx.x;
  #pragma unroll
  for (int i = 0; i < 6; ++i){
    int e = tid + 256*i;
    float v = (e < 512) ? Wih[(long)row*512 + e] : Whh[(long)row*1024 + (e-512)];
    unsigned short s0,s1,s2; split3(v, s0,s1,s2);
    d0[(long)row*1536 + e] = s0;
    d1[(long)row*1536 + e] = s1;
    d2[(long)row*1536 + e] = s2;
  }
}

__global__ __launch_bounds__(256) void k_prep_xe(
    const int* __restrict__ src, const float* __restrict__ enc_emb,
    unsigned short* __restrict__ X0, unsigned short* __restrict__ X1, unsigned short* __restrict__ X2)
{
  const int b = blockIdx.x, tid = threadIdx.x;
  const int t = b >> 6, m = b & 63;
  const float* srow = enc_emb + (long)src[m*Sv + t]*Ed;
  const long off = ((long)t*64 + m)*Ed;
  #pragma unroll
  for (int i = 0; i < 2; ++i){
    int e = tid + 256*i;
    unsigned short s0,s1,s2; split3(srow[e], s0,s1,s2);
    X0[off+e] = s0; X1[off+e] = s1; X2[off+e] = s2;
  }
}

// ---------------- grid barrier ----------------
// Arrive: release-RMW (writes back dirty L2 once). Spin: RELAXED agent loads —
// scope bits bypass L2 (sees remote updates) but emit NO buffer_inv per poll.
// One acquire fence after exit invalidates L1/L2 exactly once per phase.
__device__ __forceinline__ void gbar(int* cnt, int idx){
  __syncthreads();
  if (threadIdx.x == 0){
    __hip_atomic_fetch_add(&cnt[idx], 1, __ATOMIC_RELEASE, __HIP_MEMORY_SCOPE_AGENT);
    while (__hip_atomic_load(&cnt[idx], __ATOMIC_RELAXED, __HIP_MEMORY_SCOPE_AGENT) < NB)
      __builtin_amdgcn_s_sleep(2);
    __builtin_amdgcn_fence(__ATOMIC_ACQUIRE, "agent");
  }
  __syncthreads();
}

// ---------------- LSTM phase (6-term fp32-equivalent, proven round 4/5) ----------------
template<bool DEC>
__device__ __forceinline__ void lstm_phase(
    int b, int tid, int tj,
    const unsigned short* __restrict__ W0s, const unsigned short* __restrict__ W1s,
    const unsigned short* __restrict__ W2s, const float* __restrict__ bias,
    const unsigned short* __restrict__ X0, const unsigned short* __restrict__ X1,
    const unsigned short* __restrict__ X2,
    const int* __restrict__ trg, const int* __restrict__ tf,
    const float* __restrict__ dec_emb, const unsigned long long* __restrict__ toku,
    const unsigned short* __restrict__ H0in, const unsigned short* __restrict__ H1in,
    const unsigned short* __restrict__ H2in,
    const float* __restrict__ c_in, float* __restrict__ c_out,
    unsigned short* __restrict__ H0o, unsigned short* __restrict__ H1o,
    unsigned short* __restrict__ H2o,
    float (*g4)[32][16], int* stok)
{
  const int g = tid >> 6, lane = tid & 63;
  const int l15 = lane & 15, lk = lane >> 4;
  const int jh0 = (b & 63) * 16;
  const int m0 = (b >> 6) * 32;
  const int n = g*Hd + jh0 + l15;
  const unsigned short* w0 = W0s + (long)n*1536;
  const unsigned short* w1 = W1s + (long)n*1536;
  const unsigned short* w2 = W2s + (long)n*1536;

  if (DEC){
    if (tid < 32){
      int m = m0 + tid, tk;
      if (tj == 0) tk = trg[m*Tv];
      else if (tf[tj] > 0) tk = trg[m*Tv + tj];
      else tk = (int)(~(unsigned)toku[(long)(tj-1)*64 + m]);
      stok[tid] = tk;
    }
    __syncthreads();
  }

  f32x4 acc0 = (f32x4){0.f,0.f,0.f,0.f};
  f32x4 acc1 = (f32x4){0.f,0.f,0.f,0.f};

  // x part: K = 0..511
  if (DEC){
    const float* e0 = dec_emb + (long)stok[l15]*Ed;
    const float* e1 = dec_emb + (long)stok[16 + l15]*Ed;
    #pragma unroll 2
    for (int kt = 0; kt < 16; ++kt){
      const int k0 = kt*32 + lk*8;
      bf16x8 b0 = *(const bf16x8*)(w0 + k0);
      bf16x8 b1v = *(const bf16x8*)(w1 + k0);
      bf16x8 b2 = *(const bf16x8*)(w2 + k0);
      bf16x8 a00,a01,a02,a10,a11,a12;
      {
        float4 pa = *(const float4*)(e0 + k0);
        float4 pb = *(const float4*)(e0 + k0 + 4);
        float fv[8] = {pa.x,pa.y,pa.z,pa.w,pb.x,pb.y,pb.z,pb.w};
        #pragma unroll
        for (int e=0;e<8;++e){ unsigned short s0,s1,s2; split3(fv[e],s0,s1,s2);
          a00[e]=(short)s0; a01[e]=(short)s1; a02[e]=(short)s2; }
      }
      {
        float4 pa = *(const float4*)(e1 + k0);
        float4 pb = *(const float4*)(e1 + k0 + 4);
        float fv[8] = {pa.x,pa.y,pa.z,pa.w,pb.x,pb.y,pb.z,pb.w};
        #pragma unroll
        for (int e=0;e<8;++e){ unsigned short s0,s1,s2; split3(fv[e],s0,s1,s2);
          a10[e]=(short)s0; a11[e]=(short)s1; a12[e]=(short)s2; }
      }
      acc0 = MF(a00,b0,acc0); acc0 = MF(a01,b0,acc0); acc0 = MF(a00,b1v,acc0);
      acc0 = MF(a02,b0,acc0); acc0 = MF(a00,b2,acc0); acc0 = MF(a01,b1v,acc0);
      acc1 = MF(a10,b0,acc1); acc1 = MF(a11,b0,acc1); acc1 = MF(a10,b1v,acc1);
      acc1 = MF(a12,b0,acc1); acc1 = MF(a10,b2,acc1); acc1 = MF(a11,b1v,acc1);
    }
  } else {
    const long ra0x = (long)(m0 + l15)*Ed;
    const long ra1x = (long)(m0 + 16 + l15)*Ed;
    #pragma unroll 2
    for (int kt = 0; kt < 16; ++kt){
      const int k0 = kt*32 + lk*8;
      bf16x8 b0 = *(const bf16x8*)(w0 + k0);
      bf16x8 b1v = *(const bf16x8*)(w1 + k0);
      bf16x8 b2 = *(const bf16x8*)(w2 + k0);
      bf16x8 a00 = *(const bf16x8*)(X0 + ra0x + k0);
      bf16x8 a01 = *(const bf16x8*)(X1 + ra0x + k0);
      bf16x8 a02 = *(const bf16x8*)(X2 + ra0x + k0);
      bf16x8 a10 = *(const bf16x8*)(X0 + ra1x + k0);
      bf16x8 a11 = *(const bf16x8*)(X1 + ra1x + k0);
      bf16x8 a12 = *(const bf16x8*)(X2 + ra1x + k0);
      acc0 = MF(a00,b0,acc0); acc0 = MF(a01,b0,acc0); acc0 = MF(a00,b1v,acc0);
      acc0 = MF(a02,b0,acc0); acc0 = MF(a00,b2,acc0); acc0 = MF(a01,b1v,acc0);
      acc1 = MF(a10,b0,acc1); acc1 = MF(a11,b0,acc1); acc1 = MF(a10,b1v,acc1);
      acc1 = MF(a12,b0,acc1); acc1 = MF(a10,b2,acc1); acc1 = MF(a11,b1v,acc1);
    }
  }
  // h part: K = 512..1535
  {
    const long ra0h = (long)(m0 + l15)*Hd;
    const long ra1h = (long)(m0 + 16 + l15)*Hd;
    #pragma unroll 2
    for (int kt = 0; kt < 32; ++kt){
      const int kw = 512 + kt*32 + lk*8;
      const int ko = kt*32 + lk*8;
      bf16x8 b0 = *(const bf16x8*)(w0 + kw);
      bf16x8 b1v = *(const bf16x8*)(w1 + kw);
      bf16x8 b2 = *(const bf16x8*)(w2 + kw);
      bf16x8 a00 = *(const bf16x8*)(H0in + ra0h + ko);
      bf16x8 a01 = *(const bf16x8*)(H1in + ra0h + ko);
      bf16x8 a02 = *(const bf16x8*)(H2in + ra0h + ko);
      bf16x8 a10 = *(const bf16x8*)(H0in + ra1h + ko);
      bf16x8 a11 = *(const bf16x8*)(H1in + ra1h + ko);
      bf16x8 a12 = *(const bf16x8*)(H2in + ra1h + ko);
      acc0 = MF(a00,b0,acc0); acc0 = MF(a01,b0,acc0); acc0 = MF(a00,b1v,acc0);
      acc0 = MF(a02,b0,acc0); acc0 = MF(a00,b2,acc0); acc0 = MF(a01,b1v,acc0);
      acc1 = MF(a10,b0,acc1); acc1 = MF(a11,b0,acc1); acc1 = MF(a10,b1v,acc1);
      acc1 = MF(a12,b0,acc1); acc1 = MF(a10,b2,acc1); acc1 = MF(a11,b1v,acc1);
    }
  }

  #pragma unroll
  for (int r = 0; r < 4; ++r){
    g4[g][lk*4 + r][l15]      = acc0[r];
    g4[g][16 + lk*4 + r][l15] = acc1[r];
  }
  __syncthreads();

  #pragma unroll
  for (int rep = 0; rep < 2; ++rep){
    const int mloc = (tid >> 4) + rep*16;
    const int cl = tid & 15;
    const int col = jh0 + cl;
    float ig = g4[0][mloc][cl] + bias[0*Hd + col];
    float fg = g4[1][mloc][cl] + bias[1*Hd + col];
    float gg = g4[2][mloc][cl] + bias[2*Hd + col];
    float og = g4[3][mloc][cl] + bias[3*Hd + col];
    long idx = (long)(m0 + mloc)*Hd + col;
    float c = c_in[idx];
    float cn = sigf(fg)*c + sigf(ig)*tanhf(gg);
    float hn = sigf(og)*tanhf(cn);
    c_out[idx] = cn;
    unsigned short s0,s1,s2; split3(hn, s0,s1,s2);
    H0o[idx] = s0; H1o[idx] = s1; H2o[idx] = s2;
  }
}

// ---------------- FC + fused argmax phase ----------------
__device__ __forceinline__ void fc_phase(
    int b, int tid, int j,
    const unsigned short* __restrict__ hhi, const unsigned short* __restrict__ hlo,
    const float* __restrict__ Wfc, const float* __restrict__ bfc,
    float* __restrict__ out, unsigned long long* __restrict__ tslot,
    unsigned long long* amax)
{
  if (tid < 64) amax[tid] = 0ULL;
  __syncthreads();
  const int wv = tid >> 6, lane = tid & 63;
  const int l15 = lane & 15, lk = lane >> 4;
  const int vbase = b*128 + wv*32;
  const int v0 = vbase + l15, v1 = vbase + 16 + l15;
  const float* w0r = Wfc + (long)v0*Hd;
  const float* w1r = Wfc + (long)v1*Hd;

  f32x4 acc[2][4];
  #pragma unroll
  for (int nv=0; nv<2; ++nv)
    #pragma unroll
    for (int mt=0; mt<4; ++mt) acc[nv][mt] = (f32x4){0.f,0.f,0.f,0.f};

  #pragma unroll 2
  for (int kt = 0; kt < 32; ++kt){
    const int k0 = kt*32 + lk*8;
    bf16x8 bh0, bl0, bh1, bl1;
    {
      float4 pa = *(const float4*)(w0r + k0);
      float4 pb = *(const float4*)(w0r + k0 + 4);
      float fv[8] = {pa.x,pa.y,pa.z,pa.w,pb.x,pb.y,pb.z,pb.w};
      #pragma unroll
      for (int e=0;e<8;++e){ unsigned short h = f2bf(fv[e]);
        bh0[e]=(short)h; bl0[e]=(short)f2bf(fv[e]-bf2f(h)); }
    }
    {
      float4 pa = *(const float4*)(w1r + k0);
      float4 pb = *(const float4*)(w1r + k0 + 4);
      float fv[8] = {pa.x,pa.y,pa.z,pa.w,pb.x,pb.y,pb.z,pb.w};
      #pragma unroll
      for (int e=0;e<8;++e){ unsigned short h = f2bf(fv[e]);
        bh1[e]=(short)h; bl1[e]=(short)f2bf(fv[e]-bf2f(h)); }
    }
    #pragma unroll
    for (int mt=0; mt<4; ++mt){
      const int row = mt*16 + l15;
      bf16x8 ah = *(const bf16x8*)(hhi + (long)row*Hd + k0);
      bf16x8 al = *(const bf16x8*)(hlo + (long)row*Hd + k0);
      acc[0][mt] = MF(ah, bh0, acc[0][mt]);
      acc[0][mt] = MF(al, bh0, acc[0][mt]);
      acc[0][mt] = MF(ah, bl0, acc[0][mt]);
      acc[1][mt] = MF(ah, bh1, acc[1][mt]);
      acc[1][mt] = MF(al, bh1, acc[1][mt]);
      acc[1][mt] = MF(ah, bl1, acc[1][mt]);
    }
  }
  float bb0 = bfc[v0], bb1 = bfc[v1];
  #pragma unroll
  for (int mt=0; mt<4; ++mt){
    #pragma unroll
    for (int r=0; r<4; ++r){
      int m = mt*16 + lk*4 + r;
      float f0 = acc[0][mt][r] + bb0;
      float f1 = acc[1][mt][r] + bb1;
      out[((long)m*Tv + (j+1))*(long)Vv + v0] = f0;
      out[((long)m*Tv + (j+1))*(long)Vv + v1] = f1;
      unsigned u0 = __float_as_uint(f0); u0 ^= (u0 >> 31) ? 0xFFFFFFFFu : 0x80000000u;
      unsigned u1 = __float_as_uint(f1); u1 ^= (u1 >> 31) ? 0xFFFFFFFFu : 0x80000000u;
      unsigned long long c0 = ((unsigned long long)u0 << 32) | (unsigned)(~v0);
      unsigned long long c1 = ((unsigned long long)u1 << 32) | (unsigned)(~v1);
      unsigned long long c = c0 > c1 ? c0 : c1;
      #pragma unroll
      for (int d=1; d<16; d<<=1){
        unsigned long long o = __shfl_xor(c, d);
        if (o > c) c = o;
      }
      if (l15 == 0) atomicMax(&amax[m], c);
    }
  }
  __syncthreads();
  if (tid < 64) atomicMax(tslot + tid, amax[tid]);
}

// ---------------- the mega kernel ----------------
__global__ __launch_bounds__(256, 1) void k_mega(
    const int* __restrict__ trg, const int* __restrict__ tf,
    const float* __restrict__ dec_emb,
    const float* __restrict__ b_e, const float* __restrict__ b_d,
    const float* __restrict__ Wfc, const float* __restrict__ bfc,
    float* __restrict__ out, float* __restrict__ ws)
{
  __shared__ float g4[4][32][16];
  __shared__ int stok[32];
  __shared__ unsigned long long amax[64];

  const int b = blockIdx.x, tid = threadIdx.x;
  float* cb[2] = { ws, ws + 65536 };
  unsigned short* HB = (unsigned short*)(ws + OFF_HB);
  unsigned short* H0[2] = { HB,          HB + 65536 };
  unsigned short* H1[2] = { HB + 131072, HB + 196608 };
  unsigned short* H2[2] = { HB + 262144, HB + 327680 };
  const unsigned short* Xe0 = (const unsigned short*)(ws + OFF_XE);
  const unsigned short* Xe1 = Xe0 + 4194304;
  const unsigned short* Xe2 = Xe0 + 8388608;
  const unsigned short* We0 = (const unsigned short*)(ws + OFF_WE);
  const unsigned short* We1 = We0 + 6291456;
  const unsigned short* We2 = We0 + 12582912;
  const unsigned short* Wd0 = (const unsigned short*)(ws + OFF_WD);
  const unsigned short* Wd1 = Wd0 + 6291456;
  const unsigned short* Wd2 = Wd0 + 12582912;
  unsigned long long* toku = (unsigned long long*)(ws + OFF_TOK);
  int* cnt = (int*)(ws + OFF_CNT);
  int bar = 0;

  // phase -1: zero c / H3 state and out[:,0,:]
  for (long i = (long)b*256 + tid; i < 327680; i += (long)NB*256) ws[i] = 0.f;
  for (long r = (long)b*256 + tid; r < (long)Bv*Vv; r += (long)NB*256){
    long m = r / Vv, v = r - m*Vv;
    out[m*(long)Tv*Vv + v] = 0.f;
  }
  gbar(cnt, bar++);

  int cur = 0;
  for (int t = 0; t < Sv; ++t){
    if (b < 128)
      lstm_phase<false>(b, tid, t, We0, We1, We2, b_e,
          Xe0 + (long)t*32768, Xe1 + (long)t*32768, Xe2 + (long)t*32768,
          (const int*)0, (const int*)0, (const float*)0, (const unsigned long long*)0,
          H0[cur], H1[cur], H2[cur], cb[cur], cb[cur^1],
          H0[cur^1], H1[cur^1], H2[cur^1], g4, stok);
    gbar(cnt, bar++);
    cur ^= 1;
  }
  for (int j = 0; j < Tv-1; ++j){
    if (b < 128)
      lstm_phase<true>(b, tid, j, Wd0, Wd1, Wd2, b_d,
          (const unsigned short*)0, (const unsigned short*)0, (const unsigned short*)0,
          trg, tf, dec_emb, toku,
          H0[cur], H1[cur], H2[cur], cb[cur], cb[cur^1],
          H0[cur^1], H1[cur^1], H2[cur^1], g4, stok);
    gbar(cnt, bar++);
    cur ^= 1;
    if (b < 250)
      fc_phase(b, tid, j, H0[cur], H1[cur], Wfc, bfc, out, toku + (long)j*64, amax);
    gbar(cnt, bar++);
  }
}

// ---------------- fallback (round-2 proven path, used only if ws too small) ----------------

__global__ __launch_bounds__(256) void k_initC(float* __restrict__ ws, float* __restrict__ out){
  long i = (long)blockIdx.x*256 + threadIdx.x;
  if (i < 262144){ ws[i] = 0.f; }
  else {
    long r = i - 262144;
    long m = r / Vv, v = r % Vv;
    out[m*Tv*(long)Vv + v] = 0.f;
  }
}

__global__ __launch_bounds__(256) void k_stepC(
    int mode, int t,
    const int* __restrict__ tok_src, const int* __restrict__ tf_mask,
    const int* __restrict__ token_buf, const float* __restrict__ emb,
    const float* __restrict__ Wih, const float* __restrict__ Whh,
    const float* __restrict__ bias,
    const float* __restrict__ h_in, const float* __restrict__ c_in,
    float* __restrict__ h_out, float* __restrict__ c_out,
    unsigned short* __restrict__ hsp_hi, unsigned short* __restrict__ hsp_lo)
{
  __shared__ __align__(16) float tile[8*1536];
  __shared__ float gbuf[4*8*32];
  __shared__ int toks[8];
  const int tid = threadIdx.x;
  const int m0 = blockIdx.y*8, jh0 = blockIdx.x*32;
  if (tid < 8){
    int m = m0 + tid; int tok;
    if (mode == 0) tok = tok_src[m*Sv + t];
    else { if (t == 0) tok = tok_src[m*Tv];
           else tok = (tf_mask[t] > 0) ? tok_src[m*Tv + t] : token_buf[m]; }
    toks[tid] = tok;
  }
  __syncthreads();
  { float4* t4 = (float4*)tile;
    #pragma unroll
    for (int r = 0; r < 12; ++r){
      int f = tid + 256*r; int row = f / 384, o = f % 384; float4 v;
      if (o < 128) v = ((const float4*)(emb + (long)toks[row]*Ed))[o];
      else         v = ((const float4*)(h_in + (long)(m0+row)*Hd))[o-128];
      t4[row*384 + o] = v; } }
  __syncthreads();
  const int g = tid >> 6, s = tid & 63, jl = s & 31, mg = s >> 5;
  const int col = g*Hd + jh0 + jl;
  const float4* wx = (const float4*)(Wih + (long)col*Ed);
  const float4* wh = (const float4*)(Whh + (long)col*Hd);
  const float4* t4 = (const float4*)tile;
  const int mb = mg*4;
  float bq = bias[col];
  float a0=bq, a1=bq, a2=bq, a3=bq;
  for (int k = 0; k < 128; ++k){
    float4 w = wx[k];
    float4 v0 = t4[(mb+0)*384 + k]; float4 v1 = t4[(mb+1)*384 + k];
    float4 v2 = t4[(mb+2)*384 + k]; float4 v3 = t4[(mb+3)*384 + k];
    a0 += w.x*v0.x + w.y*v0.y + w.z*v0.z + w.w*v0.w;
    a1 += w.x*v1.x + w.y*v1.y + w.z*v1.z + w.w*v1.w;
    a2 += w.x*v2.x + w.y*v2.y + w.z*v2.z + w.w*v2.w;
    a3 += w.x*v3.x + w.y*v3.y + w.z*v3.z + w.w*v3.w;
  }
  for (int k = 0; k < 256; ++k){
    float4 w = wh[k];
    float4 v0 = t4[(mb+0)*384 + 128 + k]; float4 v1 = t4[(mb+1)*384 + 128 + k];
    float4 v2 = t4[(mb+2)*384 + 128 + k]; float4 v3 = t4[(mb+3)*384 + 128 + k];
    a0 += w.x*v0.x + w.y*v0.y + w.z*v0.z + w.w*v0.w;
    a1 += w.x*v1.x + w.y*v1.y + w.z*v1.z + w.w*v1.w;
    a2 += w.x*v2.x + w.y*v2.y + w.z*v2.z + w.w*v2.w;
    a3 += w.x*v3.x + w.y*v3.y + w.z*v3.z + w.w*v3.w;
  }
  gbuf[g*256 + (mb+0)*32 + jl] = a0; gbuf[g*256 + (mb+1)*32 + jl] = a1;
  gbuf[g*256 + (mb+2)*32 + jl] = a2; gbuf[g*256 + (mb+3)*32 + jl] = a3;
  __syncthreads();
  const int ml = tid >> 5, j2 = tid & 31;
  float ig = gbuf[0*256 + ml*32 + j2];
  float fg = gbuf[1*256 + ml*32 + j2];
  float gg = gbuf[2*256 + ml*32 + j2];
  float og = gbuf[3*256 + ml*32 + j2];
  long idx = (long)(m0+ml)*Hd + jh0 + j2;
  float c = c_in[idx];
  float cn = sigf(fg)*c + sigf(ig)*tanhf(gg);
  float hn = sigf(og)*tanhf(cn);
  c_out[idx] = cn; h_out[idx] = hn;
  unsigned short hh = f2bf(hn);
  hsp_hi[idx] = hh; hsp_lo[idx] = f2bf(hn - bf2f(hh));
}

__global__ __launch_bounds__(256) void k_fcC(
    int j, const unsigned short* __restrict__ hhi, const unsigned short* __restrict__ hlo,
    const float* __restrict__ Wfc, const float* __restrict__ bfc, float* __restrict__ out)
{
  const int tid = threadIdx.x;
  const int wv = tid >> 6, lane = tid & 63;
  const int l15 = lane & 15, lk = lane >> 4;
  const int vcol = blockIdx.x*64 + wv*16 + l15;
  const float* wrow = Wfc + (long)vcol*Hd;
  f32x4 acc[4];
  #pragma unroll
  for (int mt=0; mt<4; ++mt) acc[mt] = (f32x4){0.f,0.f,0.f,0.f};
  #pragma unroll 2
  for (int kt = 0; kt < 32; ++kt){
    const int k0 = kt*32 + lk*8;
    float4 wa = *(const float4*)(wrow + k0);
    float4 wb = *(const float4*)(wrow + k0 + 4);
    float wf[8] = {wa.x,wa.y,wa.z,wa.w,wb.x,wb.y,wb.z,wb.w};
    bf16x8 bh, bl;
    #pragma unroll
    for (int e=0;e<8;++e){
      unsigned short h = f2bf(wf[e]);
      bh[e] = (short)h; bl[e] = (short)f2bf(wf[e] - bf2f(h));
    }
    #pragma unroll
    for (int mt=0; mt<4; ++mt){
      const int row = mt*16 + l15;
      bf16x8 ah = *(const bf16x8*)(hhi + row*Hd + k0);
      bf16x8 al = *(const bf16x8*)(hlo + row*Hd + k0);
      acc[mt] = MF(ah, bh, acc[mt]);
      acc[mt] = MF(al, bh, acc[mt]);
      acc[mt] = MF(ah, bl, acc[mt]);
    }
  }
  float bb = bfc[vcol];
  #pragma unroll
  for (int mt=0; mt<4; ++mt)
    #pragma unroll
    for (int r=0; r<4; ++r){
      int m = mt*16 + lk*4 + r;
      out[((long)m*Tv + (j+1))*(long)Vv + vcol] = acc[mt][r] + bb;
    }
}

__global__ __launch_bounds__(256) void k_argmaxC(
    int j, const float* __restrict__ out, int* __restrict__ token_buf)
{
  __shared__ float sval[256];
  __shared__ int   sidx[256];
  const int m = blockIdx.x, tid = threadIdx.x;
  const float* base = out + ((long)m*Tv + (j+1))*(long)Vv;
  float best = -INFINITY; int bi = 0;
  for (int v = tid; v < Vv; v += 256){
    float f = base[v];
    if (f > best){ best = f; bi = v; }
  }
  sval[tid] = best; sidx[tid] = bi;
  __syncthreads();
  for (int s2 = 128; s2 > 0; s2 >>= 1){
    if (tid < s2){
      float ov = sval[tid+s2]; int oi = sidx[tid+s2];
      if (ov > sval[tid] || (ov == sval[tid] && oi < sidx[tid])){
        sval[tid] = ov; sidx[tid] = oi;
      }
    }
    __syncthreads();
  }
  if (tid == 0) token_buf[m] = sidx[0];
}

extern "C" void kernel_launch(void* const* d_in, const int* in_sizes, int n_in,
                              void* d_out, int out_size, void* d_ws, size_t ws_size,
                              hipStream_t stream)
{
  const int*   src     = (const int*)  d_in[0];
  const int*   trg     = (const int*)  d_in[1];
  const int*   tf      = (const int*)  d_in[2];
  const float* enc_emb = (const float*)d_in[3];
  const float* dec_emb = (const float*)d_in[4];
  const float* Wih_e   = (const float*)d_in[5];
  const float* Whh_e   = (const float*)d_in[6];
  const float* b_e     = (const float*)d_in[7];
  const float* Wih_d   = (const float*)d_in[8];
  const float* Whh_d   = (const float*)d_in[9];
  const float* b_d     = (const float*)d_in[10];
  const float* Wfc     = (const float*)d_in[11];
  const float* bfc     = (const float*)d_in[12];
  float* out = (float*)d_out;
  float* ws  = (float*)d_ws;

  if (ws_size >= (size_t)NEED_FL * 4ULL){
    unsigned short* We0 = (unsigned short*)(ws + OFF_WE);
    unsigned short* We1 = We0 + 6291456;
    unsigned short* We2 = We0 + 12582912;
    unsigned short* Wd0 = (unsigned short*)(ws + OFF_WD);
    unsigned short* Wd1 = Wd0 + 6291456;
    unsigned short* Wd2 = Wd0 + 12582912;
    unsigned short* Xe0 = (unsigned short*)(ws + OFF_XE);
    unsigned short* Xe1 = Xe0 + 4194304;
    unsigned short* Xe2 = Xe0 + 8388608;

    hipMemsetAsync((void*)(ws + OFF_TOK), 0, (size_t)(NEED_FL - OFF_TOK) * 4ULL, stream);
    k_wsplit3<<<4096, 256, 0, stream>>>(Wih_e, Whh_e, We0, We1, We2);
    k_wsplit3<<<4096, 256, 0, stream>>>(Wih_d, Whh_d, Wd0, Wd1, Wd2);
    k_prep_xe<<<8192, 256, 0, stream>>>(src, enc_emb, Xe0, Xe1, Xe2);
    k_mega<<<NB, 256, 0, stream>>>(trg, tf, dec_emb, b_e, b_d, Wfc, bfc, out, ws);
  } else {
    // fallback: round-2 proven multi-kernel path
    float* hbuf[2] = { ws,            ws + 65536 };
    float* cbuf[2] = { ws + 131072,   ws + 196608 };
    int*   tokbuf  = (int*)(ws + 262144);
    unsigned short* hsp_hi = (unsigned short*)(ws + 262208);
    unsigned short* hsp_lo = (unsigned short*)(ws + 262208 + 32768);

    k_initC<<<9024, 256, 0, stream>>>(ws, out);
    int cur = 0;
    for (int t = 0; t < Sv; ++t){
      k_stepC<<<dim3(32,8), 256, 0, stream>>>(0, t, src, tf, tokbuf, enc_emb,
          Wih_e, Whh_e, b_e, hbuf[cur], cbuf[cur], hbuf[cur^1], cbuf[cur^1], hsp_hi, hsp_lo);
      cur ^= 1;
    }
    for (int j = 0; j < Tv-1; ++j){
      k_stepC<<<dim3(32,8), 256, 0, stream>>>(1, j, trg, tf, tokbuf, dec_emb,
          Wih_d, Whh_d, b_d, hbuf[cur], cbuf[cur], hbuf[cur^1], cbuf[cur^1], hsp_hi, hsp_lo);
      cur ^= 1;
      k_fcC<<<500, 256, 0, stream>>>(j, hsp_hi, hsp_lo, Wfc, bfc, out);
      if (j < Tv-2) k_argmaxC<<<64, 256, 0, stream>>>(j, out, tokbuf);
    }
  }
}

// Round 8
// 14918.095 us; speedup vs baseline: 1.7350x; 1.1706x over previous
//
#include <hip/hip_runtime.h>
#include <math.h>

#define Hd 1024
#define Ed 512
#define Bv 64
#define Sv 128
#define Tv 64
#define Vv 32000
#define NB 256

typedef __attribute__((ext_vector_type(8))) short bf16x8;
typedef __attribute__((ext_vector_type(4))) float f32x4;

__device__ __forceinline__ float sigf(float x){ return 1.0f/(1.0f + expf(-x)); }
__device__ __forceinline__ unsigned short f2bf(float f){
  unsigned u = __float_as_uint(f);
  return (unsigned short)((u + 0x7FFFu + ((u>>16)&1u)) >> 16);
}
__device__ __forceinline__ float bf2f(unsigned short b){ return __uint_as_float(((unsigned)b)<<16); }
__device__ __forceinline__ void split3(float v, unsigned short& s0, unsigned short& s1, unsigned short& s2){
  s0 = f2bf(v);
  float r1 = v - bf2f(s0);
  s1 = f2bf(r1);
  s2 = f2bf(r1 - bf2f(s1));
}
#define MF(A,B,C) __builtin_amdgcn_mfma_f32_16x16x32_bf16(A,B,C,0,0,0)

// ---- ws layout (float offsets) ----
// [0,65536)              c (in-place, block-private)
// [65536,+18874368)      H write-once slots: 3 planes x 192 slots x 64x1024 bf16
// OFF_XE .. +6291456     Xe 3 planes [128][64][512]
// OFF_WE/OFF_WD          W 3 planes [4096][1536]
// OFF_TOK                63*64 u64 argmax slots (memset 0)
// OFF_CNT                512 int barrier counters (memset 0)
#define OFF_H    65536
#define H_PL     12582912L   // shorts per H plane (192*65536)
#define OFF_XE   18939904
#define XE_PL    4194304L    // shorts per Xe plane
#define OFF_WE   25231360
#define OFF_WD   34668544
#define W_PL     6291456L    // shorts per W plane
#define OFF_TOK  44105728
#define OFF_CNT  44113792
#define NEED_FL  44114304    // ~176.5 MB

// ---------------- prep kernels ----------------

__global__ __launch_bounds__(256) void k_wsplit3(
    const float* __restrict__ Wih, const float* __restrict__ Whh,
    unsigned short* __restrict__ d0, unsigned short* __restrict__ d1, unsigned short* __restrict__ d2)
{
  const int row = blockIdx.x;
  const int tid = threadIdx.x;
  #pragma unroll
  for (int i = 0; i < 6; ++i){
    int e = tid + 256*i;
    float v = (e < 512) ? Wih[(long)row*512 + e] : Whh[(long)row*1024 + (e-512)];
    unsigned short s0,s1,s2; split3(v, s0,s1,s2);
    d0[(long)row*1536 + e] = s0;
    d1[(long)row*1536 + e] = s1;
    d2[(long)row*1536 + e] = s2;
  }
}

__global__ __launch_bounds__(256) void k_prep_xe(
    const int* __restrict__ src, const float* __restrict__ enc_emb,
    unsigned short* __restrict__ X0, unsigned short* __restrict__ X1, unsigned short* __restrict__ X2)
{
  const int b = blockIdx.x, tid = threadIdx.x;
  const int t = b >> 6, m = b & 63;
  const float* srow = enc_emb + (long)src[m*Sv + t]*Ed;
  const long off = ((long)t*64 + m)*Ed;
  #pragma unroll
  for (int i = 0; i < 2; ++i){
    int e = tid + 256*i;
    unsigned short s0,s1,s2; split3(srow[e], s0,s1,s2);
    X0[off+e] = s0; X1[off+e] = s1; X2[off+e] = s2;
  }
}

// ---------------- grid barrier (no agent acquire-inv: data goes via LLC atomics / write-once) ----------------
__device__ __forceinline__ void gbar(int* cnt, int idx){
  __syncthreads();
  if (threadIdx.x == 0){
    __hip_atomic_fetch_add(&cnt[idx], 1, __ATOMIC_RELEASE, __HIP_MEMORY_SCOPE_AGENT);
    while (__hip_atomic_load(&cnt[idx], __ATOMIC_RELAXED, __HIP_MEMORY_SCOPE_AGENT) < NB)
      __builtin_amdgcn_s_sleep(2);
    __builtin_amdgcn_fence(__ATOMIC_ACQUIRE, "workgroup");
  }
  __syncthreads();
}

// ---------------- LSTM phase: 256 blocks, 16 rows x 16 cols x 4 gates each ----------------
template<bool DEC>
__device__ __forceinline__ void lstm_phase(
    int b, int tid, int slot, int tj,
    const unsigned short* __restrict__ W0s, const unsigned short* __restrict__ W1s,
    const unsigned short* __restrict__ W2s, const float* __restrict__ bias,
    const unsigned short* __restrict__ Xe,     // plane0 (enc only)
    const int* __restrict__ trg, const int* __restrict__ tf,
    const float* __restrict__ dec_emb, const unsigned long long* __restrict__ toku,
    unsigned short* __restrict__ H,            // plane0 base
    float* __restrict__ c,
    float (*g4)[16][16], short (*hst)[16][16], int* stok)
{
  const int g = tid >> 6, lane = tid & 63;
  const int l15 = lane & 15, lk = lane >> 4;
  const int jh = (b & 63) * 16;
  const int m0 = (b >> 6) * 16;
  const int n = g*Hd + jh + l15;
  const unsigned short* w0 = W0s + (long)n*1536;
  const unsigned short* w1 = W1s + (long)n*1536;
  const unsigned short* w2 = W2s + (long)n*1536;
  const unsigned short* h0 = H + (long)slot*65536;
  const unsigned short* h1 = h0 + H_PL;
  const unsigned short* h2 = h0 + 2*H_PL;

  if (DEC){
    if (tid < 16){
      int m = m0 + tid, tk;
      if (tj == 0) tk = trg[m*Tv];
      else if (tf[tj] > 0) tk = trg[m*Tv + tj];
      else tk = (int)(~(unsigned)__hip_atomic_load(&toku[(long)(tj-1)*64 + m],
                     __ATOMIC_RELAXED, __HIP_MEMORY_SCOPE_AGENT));
      stok[tid] = tk;
    }
    __syncthreads();
  }

  f32x4 acc = (f32x4){0.f,0.f,0.f,0.f};

  // x part: K = 0..511
  if (DEC){
    const float* e0 = dec_emb + (long)stok[l15]*Ed;
    #pragma unroll 2
    for (int kt = 0; kt < 16; ++kt){
      const int k0 = kt*32 + lk*8;
      bf16x8 b0 = *(const bf16x8*)(w0 + k0);
      bf16x8 b1v = *(const bf16x8*)(w1 + k0);
      bf16x8 b2 = *(const bf16x8*)(w2 + k0);
      bf16x8 a0,a1,a2;
      float4 pa = *(const float4*)(e0 + k0);
      float4 pb = *(const float4*)(e0 + k0 + 4);
      float fv[8] = {pa.x,pa.y,pa.z,pa.w,pb.x,pb.y,pb.z,pb.w};
      #pragma unroll
      for (int e=0;e<8;++e){ unsigned short s0,s1,s2; split3(fv[e],s0,s1,s2);
        a0[e]=(short)s0; a1[e]=(short)s1; a2[e]=(short)s2; }
      acc = MF(a0,b0,acc); acc = MF(a1,b0,acc); acc = MF(a0,b1v,acc);
      acc = MF(a2,b0,acc); acc = MF(a0,b2,acc); acc = MF(a1,b1v,acc);
    }
  } else {
    const long rx = ((long)tj*64 + m0 + l15)*Ed;
    #pragma unroll 2
    for (int kt = 0; kt < 16; ++kt){
      const int k0 = kt*32 + lk*8;
      bf16x8 b0 = *(const bf16x8*)(w0 + k0);
      bf16x8 b1v = *(const bf16x8*)(w1 + k0);
      bf16x8 b2 = *(const bf16x8*)(w2 + k0);
      bf16x8 a0 = *(const bf16x8*)(Xe + rx + k0);
      bf16x8 a1 = *(const bf16x8*)(Xe + XE_PL + rx + k0);
      bf16x8 a2 = *(const bf16x8*)(Xe + 2*XE_PL + rx + k0);
      acc = MF(a0,b0,acc); acc = MF(a1,b0,acc); acc = MF(a0,b1v,acc);
      acc = MF(a2,b0,acc); acc = MF(a0,b2,acc); acc = MF(a1,b1v,acc);
    }
  }
  // h part: K = 512..1535
  {
    const long rh = (long)(m0 + l15)*Hd;
    #pragma unroll 2
    for (int kt = 0; kt < 32; ++kt){
      const int kw = 512 + kt*32 + lk*8;
      const int ko = kt*32 + lk*8;
      bf16x8 b0 = *(const bf16x8*)(w0 + kw);
      bf16x8 b1v = *(const bf16x8*)(w1 + kw);
      bf16x8 b2 = *(const bf16x8*)(w2 + kw);
      bf16x8 a0 = *(const bf16x8*)(h0 + rh + ko);
      bf16x8 a1 = *(const bf16x8*)(h1 + rh + ko);
      bf16x8 a2 = *(const bf16x8*)(h2 + rh + ko);
      acc = MF(a0,b0,acc); acc = MF(a1,b0,acc); acc = MF(a0,b1v,acc);
      acc = MF(a2,b0,acc); acc = MF(a0,b2,acc); acc = MF(a1,b1v,acc);
    }
  }

  // C/D: col=lane&15, row=(lane>>4)*4+r  -> [m-local][col-local]
  #pragma unroll
  for (int r = 0; r < 4; ++r) g4[g][lk*4 + r][l15] = acc[r];
  __syncthreads();

  {
    const int mloc = tid >> 4, cl = tid & 15;
    const int col = jh + cl;
    float ig = g4[0][mloc][cl] + bias[col];
    float fg = g4[1][mloc][cl] + bias[Hd + col];
    float gg = g4[2][mloc][cl] + bias[2*Hd + col];
    float og = g4[3][mloc][cl] + bias[3*Hd + col];
    long idx = (long)(m0 + mloc)*Hd + col;
    float cv = c[idx];
    float cn = sigf(fg)*cv + sigf(ig)*tanhf(gg);
    float hn = sigf(og)*tanhf(cn);
    c[idx] = cn;
    unsigned short s0,s1,s2; split3(hn, s0,s1,s2);
    hst[0][mloc][cl] = (short)s0; hst[1][mloc][cl] = (short)s1; hst[2][mloc][cl] = (short)s2;
  }
  __syncthreads();
  // write-once H slot+1 via 8B agent atomic stores (write-through, no L2 allocation)
  if (tid < 192){
    const int p = tid >> 6, t2 = tid & 63, r = t2 >> 2, q = t2 & 3;
    unsigned long long v =
        (unsigned long long)(unsigned short)hst[p][r][q*4]
      | ((unsigned long long)(unsigned short)hst[p][r][q*4+1] << 16)
      | ((unsigned long long)(unsigned short)hst[p][r][q*4+2] << 32)
      | ((unsigned long long)(unsigned short)hst[p][r][q*4+3] << 48);
    unsigned long long* dst = (unsigned long long*)
        (H + (long)p*H_PL + (long)(slot+1)*65536 + (long)(m0 + r)*Hd + jh + q*4);
    __hip_atomic_store(dst, v, __ATOMIC_RELAXED, __HIP_MEMORY_SCOPE_AGENT);
  }
}

// ---------------- argmax-only FC phase (runs only when tf[j+1]==0) ----------------
__device__ __forceinline__ void fc_phase(
    int b, int tid, int j,
    const unsigned short* __restrict__ hhi, const unsigned short* __restrict__ hlo,
    const float* __restrict__ Wfc, const float* __restrict__ bfc,
    unsigned long long* __restrict__ tslot, unsigned long long* amax)
{
  if (tid < 64) amax[tid] = 0ULL;
  __syncthreads();
  const int wv = tid >> 6, lane = tid & 63;
  const int l15 = lane & 15, lk = lane >> 4;
  const int vbase = b*128 + wv*32;
  const int v0 = vbase + l15, v1 = vbase + 16 + l15;
  const float* w0r = Wfc + (long)v0*Hd;
  const float* w1r = Wfc + (long)v1*Hd;

  f32x4 acc[2][4];
  #pragma unroll
  for (int nv=0; nv<2; ++nv)
    #pragma unroll
    for (int mt=0; mt<4; ++mt) acc[nv][mt] = (f32x4){0.f,0.f,0.f,0.f};

  #pragma unroll 2
  for (int kt = 0; kt < 32; ++kt){
    const int k0 = kt*32 + lk*8;
    bf16x8 bh0, bl0, bh1, bl1;
    {
      float4 pa = *(const float4*)(w0r + k0);
      float4 pb = *(const float4*)(w0r + k0 + 4);
      float fv[8] = {pa.x,pa.y,pa.z,pa.w,pb.x,pb.y,pb.z,pb.w};
      #pragma unroll
      for (int e=0;e<8;++e){ unsigned short h = f2bf(fv[e]);
        bh0[e]=(short)h; bl0[e]=(short)f2bf(fv[e]-bf2f(h)); }
    }
    {
      float4 pa = *(const float4*)(w1r + k0);
      float4 pb = *(const float4*)(w1r + k0 + 4);
      float fv[8] = {pa.x,pa.y,pa.z,pa.w,pb.x,pb.y,pb.z,pb.w};
      #pragma unroll
      for (int e=0;e<8;++e){ unsigned short h = f2bf(fv[e]);
        bh1[e]=(short)h; bl1[e]=(short)f2bf(fv[e]-bf2f(h)); }
    }
    #pragma unroll
    for (int mt=0; mt<4; ++mt){
      const int row = mt*16 + l15;
      bf16x8 ah = *(const bf16x8*)(hhi + (long)row*Hd + k0);
      bf16x8 al = *(const bf16x8*)(hlo + (long)row*Hd + k0);
      acc[0][mt] = MF(ah, bh0, acc[0][mt]);
      acc[0][mt] = MF(al, bh0, acc[0][mt]);
      acc[0][mt] = MF(ah, bl0, acc[0][mt]);
      acc[1][mt] = MF(ah, bh1, acc[1][mt]);
      acc[1][mt] = MF(al, bh1, acc[1][mt]);
      acc[1][mt] = MF(ah, bl1, acc[1][mt]);
    }
  }
  float bb0 = bfc[v0], bb1 = bfc[v1];
  #pragma unroll
  for (int mt=0; mt<4; ++mt){
    #pragma unroll
    for (int r=0; r<4; ++r){
      int m = mt*16 + lk*4 + r;
      float f0 = acc[0][mt][r] + bb0;
      float f1 = acc[1][mt][r] + bb1;
      unsigned u0 = __float_as_uint(f0); u0 ^= (u0 >> 31) ? 0xFFFFFFFFu : 0x80000000u;
      unsigned u1 = __float_as_uint(f1); u1 ^= (u1 >> 31) ? 0xFFFFFFFFu : 0x80000000u;
      unsigned long long c0 = ((unsigned long long)u0 << 32) | (unsigned)(~v0);
      unsigned long long c1 = ((unsigned long long)u1 << 32) | (unsigned)(~v1);
      unsigned long long cm = c0 > c1 ? c0 : c1;
      #pragma unroll
      for (int d=1; d<16; d<<=1){
        unsigned long long o = __shfl_xor(cm, d);
        if (o > cm) cm = o;
      }
      if (l15 == 0) atomicMax(&amax[m], cm);
    }
  }
  __syncthreads();
  if (tid < 64) atomicMax(tslot + tid, amax[tid]);
}

// ---------------- the mega kernel ----------------
__global__ __launch_bounds__(256, 1) void k_mega(
    const int* __restrict__ trg, const int* __restrict__ tf,
    const float* __restrict__ dec_emb,
    const float* __restrict__ b_e, const float* __restrict__ b_d,
    const float* __restrict__ Wfc, const float* __restrict__ bfc,
    float* __restrict__ ws)
{
  __shared__ float g4[4][16][16];
  __shared__ short hst[3][16][16];
  __shared__ int stok[16];
  __shared__ unsigned long long amax[64];

  const int b = blockIdx.x, tid = threadIdx.x;
  float* c = ws;
  unsigned short* H = (unsigned short*)(ws + OFF_H);
  const unsigned short* Xe  = (const unsigned short*)(ws + OFF_XE);
  const unsigned short* We0 = (const unsigned short*)(ws + OFF_WE);
  const unsigned short* We1 = We0 + W_PL;
  const unsigned short* We2 = We0 + 2*W_PL;
  const unsigned short* Wd0 = (const unsigned short*)(ws + OFF_WD);
  const unsigned short* Wd1 = Wd0 + W_PL;
  const unsigned short* Wd2 = Wd0 + 2*W_PL;
  unsigned long long* toku = (unsigned long long*)(ws + OFF_TOK);
  int* cnt = (int*)(ws + OFF_CNT);
  int bar = 0;

  // init: zero own c tile (block-private) + stripe of H slot 0 (atomic write-through)
  // slot 0 total = 3 planes x 8192 ULL = 24576 ULL = 256 blocks x 96
  {
    const int jh = (b & 63)*16, m0 = (b >> 6)*16;
    const int mloc = tid >> 4, cl = tid & 15;
    c[(long)(m0+mloc)*Hd + jh + cl] = 0.f;
    if (tid < 96){
      long off_ull = (long)b*96 + tid;       // 0 .. 24575
      int p = (int)(off_ull >> 13);          // 8192 ull per plane-slot0 -> p in {0,1,2}
      long q = off_ull & 8191;
      unsigned long long* dst = (unsigned long long*)(H + (long)p*H_PL) + q;
      __hip_atomic_store(dst, 0ULL, __ATOMIC_RELAXED, __HIP_MEMORY_SCOPE_AGENT);
    }
  }
  gbar(cnt, bar++);

  int s = 0;
  for (int t = 0; t < Sv; ++t){
    lstm_phase<false>(b, tid, s, t, We0, We1, We2, b_e, Xe,
        (const int*)0, (const int*)0, (const float*)0, (const unsigned long long*)0,
        H, c, g4, hst, stok);
    gbar(cnt, bar++); ++s;
  }
  for (int j = 0; j < Tv-1; ++j){
    lstm_phase<true>(b, tid, s, j, Wd0, Wd1, Wd2, b_d, (const unsigned short*)0,
        trg, tf, dec_emb, toku, H, c, g4, hst, stok);
    gbar(cnt, bar++); ++s;
    if (j < Tv-2 && tf[j+1] == 0){     // argmax needed only for free-running next step
      if (b < 250){
        const unsigned short* h0 = H + (long)s*65536;
        fc_phase(b, tid, j, h0, h0 + H_PL, Wfc, bfc, toku + (long)j*64, amax);
      }
      gbar(cnt, bar++);
    }
  }
}

// ---------------- batched logits: out[:, j+1, :] for all j, Wfc read 8x total ----------------
__global__ void k_fcall(
    const float* __restrict__ Wfc, const float* __restrict__ bfc,
    const unsigned short* __restrict__ H, float* __restrict__ out)
{
  const int tid = threadIdx.x;
  const int wv = tid >> 6, lane = tid & 63;
  const int l15 = lane & 15, lk = lane >> 4;
  const int vcol = blockIdx.x*64 + wv*16 + l15;
  const int jbase = blockIdx.y*8;
  const float* wr = Wfc + (long)vcol*Hd;
  const unsigned short* h0b = H + (long)(129 + jbase)*65536;
  const unsigned short* h1b = h0b + H_PL;

  f32x4 acc[8][4];
  #pragma unroll
  for (int jj=0;jj<8;++jj)
    #pragma unroll
    for (int mt=0;mt<4;++mt) acc[jj][mt] = (f32x4){0.f,0.f,0.f,0.f};

  for (int kt = 0; kt < 32; ++kt){
    const int k0 = kt*32 + lk*8;
    bf16x8 bh, bl;
    {
      float4 pa = *(const float4*)(wr + k0);
      float4 pb = *(const float4*)(wr + k0 + 4);
      float fv[8] = {pa.x,pa.y,pa.z,pa.w,pb.x,pb.y,pb.z,pb.w};
      #pragma unroll
      for (int e=0;e<8;++e){ unsigned short h = f2bf(fv[e]);
        bh[e]=(short)h; bl[e]=(short)f2bf(fv[e]-bf2f(h)); }
    }
    #pragma unroll
    for (int jj=0;jj<8;++jj){
      if (jbase + jj <= 62){
        #pragma unroll
        for (int mt=0;mt<4;++mt){
          const int row = mt*16 + l15;
          bf16x8 ah = *(const bf16x8*)(h0b + (long)jj*65536 + (long)row*Hd + k0);
          bf16x8 al = *(const bf16x8*)(h1b + (long)jj*65536 + (long)row*Hd + k0);
          acc[jj][mt] = MF(ah, bh, acc[jj][mt]);
          acc[jj][mt] = MF(al, bh, acc[jj][mt]);
          acc[jj][mt] = MF(ah, bl, acc[jj][mt]);
        }
      }
    }
  }
  float bb = bfc[vcol];
  #pragma unroll
  for (int jj=0;jj<8;++jj){
    if (jbase + jj <= 62){
      #pragma unroll
      for (int mt=0;mt<4;++mt){
        #pragma unroll
        for (int r=0;r<4;++r){
          int m = mt*16 + lk*4 + r;
          out[((long)m*Tv + (jbase+jj+1))*(long)Vv + vcol] = acc[jj][mt][r] + bb;
        }
      }
    }
  }
  if (blockIdx.y == 0){
    const int vb = blockIdx.x*64;
    for (int i = tid; i < 4096; i += 256){
      int m = i >> 6, v = vb + (i & 63);
      out[(long)m*Tv*(long)Vv + v] = 0.f;
    }
  }
}

// ---------------- fallback (round-2 proven path, used only if ws too small) ----------------

__global__ __launch_bounds__(256) void k_initC(float* __restrict__ ws, float* __restrict__ out){
  long i = (long)blockIdx.x*256 + threadIdx.x;
  if (i < 262144){ ws[i] = 0.f; }
  else {
    long r = i - 262144;
    long m = r / Vv, v = r % Vv;
    out[m*Tv*(long)Vv + v] = 0.f;
  }
}

__global__ __launch_bounds__(256) void k_stepC(
    int mode, int t,
    const int* __restrict__ tok_src, const int* __restrict__ tf_mask,
    const int* __restrict__ token_buf, const float* __restrict__ emb,
    const float* __restrict__ Wih, const float* __restrict__ Whh,
    const float* __restrict__ bias,
    const float* __restrict__ h_in, const float* __restrict__ c_in,
    float* __restrict__ h_out, float* __restrict__ c_out,
    unsigned short* __restrict__ hsp_hi, unsigned short* __restrict__ hsp_lo)
{
  __shared__ __align__(16) float tile[8*1536];
  __shared__ float gbuf[4*8*32];
  __shared__ int toks[8];
  const int tid = threadIdx.x;
  const int m0 = blockIdx.y*8, jh0 = blockIdx.x*32;
  if (tid < 8){
    int m = m0 + tid; int tok;
    if (mode == 0) tok = tok_src[m*Sv + t];
    else { if (t == 0) tok = tok_src[m*Tv];
           else tok = (tf_mask[t] > 0) ? tok_src[m*Tv + t] : token_buf[m]; }
    toks[tid] = tok;
  }
  __syncthreads();
  { float4* t4 = (float4*)tile;
    #pragma unroll
    for (int r = 0; r < 12; ++r){
      int f = tid + 256*r; int row = f / 384, o = f % 384; float4 v;
      if (o < 128) v = ((const float4*)(emb + (long)toks[row]*Ed))[o];
      else         v = ((const float4*)(h_in + (long)(m0+row)*Hd))[o-128];
      t4[row*384 + o] = v; } }
  __syncthreads();
  const int g = tid >> 6, sx = tid & 63, jl = sx & 31, mg = sx >> 5;
  const int col = g*Hd + jh0 + jl;
  const float4* wx = (const float4*)(Wih + (long)col*Ed);
  const float4* wh = (const float4*)(Whh + (long)col*Hd);
  const float4* t4 = (const float4*)tile;
  const int mb = mg*4;
  float bq = bias[col];
  float a0=bq, a1=bq, a2=bq, a3=bq;
  for (int k = 0; k < 128; ++k){
    float4 w = wx[k];
    float4 v0 = t4[(mb+0)*384 + k]; float4 v1 = t4[(mb+1)*384 + k];
    float4 v2 = t4[(mb+2)*384 + k]; float4 v3 = t4[(mb+3)*384 + k];
    a0 += w.x*v0.x + w.y*v0.y + w.z*v0.z + w.w*v0.w;
    a1 += w.x*v1.x + w.y*v1.y + w.z*v1.z + w.w*v1.w;
    a2 += w.x*v2.x + w.y*v2.y + w.z*v2.z + w.w*v2.w;
    a3 += w.x*v3.x + w.y*v3.y + w.z*v3.z + w.w*v3.w;
  }
  for (int k = 0; k < 256; ++k){
    float4 w = wh[k];
    float4 v0 = t4[(mb+0)*384 + 128 + k]; float4 v1 = t4[(mb+1)*384 + 128 + k];
    float4 v2 = t4[(mb+2)*384 + 128 + k]; float4 v3 = t4[(mb+3)*384 + 128 + k];
    a0 += w.x*v0.x + w.y*v0.y + w.z*v0.z + w.w*v0.w;
    a1 += w.x*v1.x + w.y*v1.y + w.z*v1.z + w.w*v1.w;
    a2 += w.x*v2.x + w.y*v2.y + w.z*v2.z + w.w*v2.w;
    a3 += w.x*v3.x + w.y*v3.y + w.z*v3.z + w.w*v3.w;
  }
  gbuf[g*256 + (mb+0)*32 + jl] = a0; gbuf[g*256 + (mb+1)*32 + jl] = a1;
  gbuf[g*256 + (mb+2)*32 + jl] = a2; gbuf[g*256 + (mb+3)*32 + jl] = a3;
  __syncthreads();
  const int ml = tid >> 5, j2 = tid & 31;
  float ig = gbuf[0*256 + ml*32 + j2];
  float fg = gbuf[1*256 + ml*32 + j2];
  float gg = gbuf[2*256 + ml*32 + j2];
  float og = gbuf[3*256 + ml*32 + j2];
  long idx = (long)(m0+ml)*Hd + jh0 + j2;
  float cc = c_in[idx];
  float cn = sigf(fg)*cc + sigf(ig)*tanhf(gg);
  float hn = sigf(og)*tanhf(cn);
  c_out[idx] = cn; h_out[idx] = hn;
  unsigned short hh = f2bf(hn);
  hsp_hi[idx] = hh; hsp_lo[idx] = f2bf(hn - bf2f(hh));
}

__global__ __launch_bounds__(256) void k_fcC(
    int j, const unsigned short* __restrict__ hhi, const unsigned short* __restrict__ hlo,
    const float* __restrict__ Wfc, const float* __restrict__ bfc, float* __restrict__ out)
{
  const int tid = threadIdx.x;
  const int wv = tid >> 6, lane = tid & 63;
  const int l15 = lane & 15, lk = lane >> 4;
  const int vcol = blockIdx.x*64 + wv*16 + l15;
  const float* wrow = Wfc + (long)vcol*Hd;
  f32x4 acc[4];
  #pragma unroll
  for (int mt=0; mt<4; ++mt) acc[mt] = (f32x4){0.f,0.f,0.f,0.f};
  #pragma unroll 2
  for (int kt = 0; kt < 32; ++kt){
    const int k0 = kt*32 + lk*8;
    float4 wa = *(const float4*)(wrow + k0);
    float4 wb = *(const float4*)(wrow + k0 + 4);
    float wf[8] = {wa.x,wa.y,wa.z,wa.w,wb.x,wb.y,wb.z,wb.w};
    bf16x8 bh, bl;
    #pragma unroll
    for (int e=0;e<8;++e){
      unsigned short h = f2bf(wf[e]);
      bh[e] = (short)h; bl[e] = (short)f2bf(wf[e] - bf2f(h));
    }
    #pragma unroll
    for (int mt=0; mt<4; ++mt){
      const int row = mt*16 + l15;
      bf16x8 ah = *(const bf16x8*)(hhi + row*Hd + k0);
      bf16x8 al = *(const bf16x8*)(hlo + row*Hd + k0);
      acc[mt] = MF(ah, bh, acc[mt]);
      acc[mt] = MF(al, bh, acc[mt]);
      acc[mt] = MF(ah, bl, acc[mt]);
    }
  }
  float bb = bfc[vcol];
  #pragma unroll
  for (int mt=0; mt<4; ++mt)
    #pragma unroll
    for (int r=0; r<4; ++r){
      int m = mt*16 + lk*4 + r;
      out[((long)m*Tv + (j+1))*(long)Vv + vcol] = acc[mt][r] + bb;
    }
}

__global__ __launch_bounds__(256) void k_argmaxC(
    int j, const float* __restrict__ out, int* __restrict__ token_buf)
{
  __shared__ float sval[256];
  __shared__ int   sidx[256];
  const int m = blockIdx.x, tid = threadIdx.x;
  const float* base = out + ((long)m*Tv + (j+1))*(long)Vv;
  float best = -INFINITY; int bi = 0;
  for (int v = tid; v < Vv; v += 256){
    float f = base[v];
    if (f > best){ best = f; bi = v; }
  }
  sval[tid] = best; sidx[tid] = bi;
  __syncthreads();
  for (int s2 = 128; s2 > 0; s2 >>= 1){
    if (tid < s2){
      float ov = sval[tid+s2]; int oi = sidx[tid+s2];
      if (ov > sval[tid] || (ov == sval[tid] && oi < sidx[tid])){
        sval[tid] = ov; sidx[tid] = oi;
      }
    }
    __syncthreads();
  }
  if (tid == 0) token_buf[m] = sidx[0];
}

extern "C" void kernel_launch(void* const* d_in, const int* in_sizes, int n_in,
                              void* d_out, int out_size, void* d_ws, size_t ws_size,
                              hipStream_t stream)
{
  const int*   src     = (const int*)  d_in[0];
  const int*   trg     = (const int*)  d_in[1];
  const int*   tf      = (const int*)  d_in[2];
  const float* enc_emb = (const float*)d_in[3];
  const float* dec_emb = (const float*)d_in[4];
  const float* Wih_e   = (const float*)d_in[5];
  const float* Whh_e   = (const float*)d_in[6];
  const float* b_e     = (const float*)d_in[7];
  const float* Wih_d   = (const float*)d_in[8];
  const float* Whh_d   = (const float*)d_in[9];
  const float* b_d     = (const float*)d_in[10];
  const float* Wfc     = (const float*)d_in[11];
  const float* bfc     = (const float*)d_in[12];
  float* out = (float*)d_out;
  float* ws  = (float*)d_ws;

  if (ws_size >= (size_t)NEED_FL * 4ULL){
    unsigned short* We0 = (unsigned short*)(ws + OFF_WE);
    unsigned short* Wd0 = (unsigned short*)(ws + OFF_WD);
    unsigned short* Xe0 = (unsigned short*)(ws + OFF_XE);
    unsigned short* Hb  = (unsigned short*)(ws + OFF_H);

    hipMemsetAsync((void*)(ws + OFF_TOK), 0, (size_t)(NEED_FL - OFF_TOK) * 4ULL, stream);
    k_wsplit3<<<4096, 256, 0, stream>>>(Wih_e, Whh_e, We0, We0 + W_PL, We0 + 2*W_PL);
    k_wsplit3<<<4096, 256, 0, stream>>>(Wih_d, Whh_d, Wd0, Wd0 + W_PL, Wd0 + 2*W_PL);
    k_prep_xe<<<8192, 256, 0, stream>>>(src, enc_emb, Xe0, Xe0 + XE_PL, Xe0 + 2*XE_PL);
    k_mega<<<NB, 256, 0, stream>>>(trg, tf, dec_emb, b_e, b_d, Wfc, bfc, ws);
    k_fcall<<<dim3(500, 8), 256, 0, stream>>>(Wfc, bfc, Hb, out);
  } else {
    // fallback: round-2 proven multi-kernel path
    float* hbuf[2] = { ws,            ws + 65536 };
    float* cbuf[2] = { ws + 131072,   ws + 196608 };
    int*   tokbuf  = (int*)(ws + 262144);
    unsigned short* hsp_hi = (unsigned short*)(ws + 262208);
    unsigned short* hsp_lo = (unsigned short*)(ws + 262208 + 32768);

    k_initC<<<9024, 256, 0, stream>>>(ws, out);
    int cur = 0;
    for (int t = 0; t < Sv; ++t){
      k_stepC<<<dim3(32,8), 256, 0, stream>>>(0, t, src, tf, tokbuf, enc_emb,
          Wih_e, Whh_e, b_e, hbuf[cur], cbuf[cur], hbuf[cur^1], cbuf[cur^1], hsp_hi, hsp_lo);
      cur ^= 1;
    }
    for (int j = 0; j < Tv-1; ++j){
      k_stepC<<<dim3(32,8), 256, 0, stream>>>(1, j, trg, tf, tokbuf, dec_emb,
          Wih_d, Whh_d, b_d, hbuf[cur], cbuf[cur], hbuf[cur^1], cbuf[cur^1], hsp_hi, hsp_lo);
      cur ^= 1;
      k_fcC<<<500, 256, 0, stream>>>(j, hsp_hi, hsp_lo, Wfc, bfc, out);
      if (j < Tv-2) k_argmaxC<<<64, 256, 0, stream>>>(j, out, tokbuf);
    }
  }
}